// Round 13
// baseline (150.035 us; speedup 1.0000x reference)
//
#include <hip/hip_runtime.h>
#include <hip/hip_bf16.h>
#include <math.h>

typedef unsigned short u16;
typedef __attribute__((ext_vector_type(2))) float f32x2;
typedef __attribute__((ext_vector_type(4))) float f32x4;
typedef __attribute__((ext_vector_type(4))) unsigned short u16x4;
typedef __attribute__((ext_vector_type(8))) short s16x8;
typedef __attribute__((ext_vector_type(4))) unsigned int u32x4;

__device__ __forceinline__ u16 f2bf(float f) {
  union { float f; unsigned int u; } v; v.f = f;
  unsigned int r = v.u + 0x7FFFu + ((v.u >> 16) & 1u);
  return (u16)(r >> 16);
}
__device__ __forceinline__ float bf2f(u16 u) {
  union { unsigned int u; float f; } v; v.u = ((unsigned int)u) << 16;
  return v.f;
}
__device__ __forceinline__ float u2f(unsigned int u) {
  union { unsigned int u; float f; } v; v.u = u;
  return v.f;
}
__device__ __forceinline__ void gload16(const void* g, void* l) {
  __builtin_amdgcn_global_load_lds(
      (const __attribute__((address_space(1))) unsigned int*)g,
      (__attribute__((address_space(3))) unsigned int*)l, 16, 0, 0);
}

// ---------------------------------------------------------------------------
// prep: blocks [0,192): LDS-tiled transpose of Wq/Wv/Wo -> bf16 (coalesced
// both sides); [192,448): Wk straight convert; [448,2496): xg row gather.
// ---------------------------------------------------------------------------
__global__ __launch_bounds__(256)
void prep_kernel(const float* __restrict__ x,
                 const float* __restrict__ Wq, const float* __restrict__ Wv,
                 const float* __restrict__ Wo, const float* __restrict__ Wk,
                 u16* __restrict__ wqT, u16* __restrict__ wvT,
                 u16* __restrict__ woT, u16* __restrict__ wkB,
                 u16* __restrict__ xg)
{
  const int blk = blockIdx.x;
  const int t = threadIdx.x;
  if (blk < 192) {
    __shared__ u16 tile[64 * 72];
    int m = blk >> 6, tno = blk & 63;
    const float* W = (m == 0) ? Wq : (m == 1) ? Wv : Wo;
    u16* WT = (m == 0) ? wqT : (m == 1) ? wvT : woT;
    int r0 = (tno >> 3) * 64, c0 = (tno & 7) * 64;
    int tr = t >> 4;            // 0..15
    int tc = (t & 15) * 4;      // 0..60
#pragma unroll
    for (int ii = 0; ii < 4; ii++) {
      int r = tr + ii * 16;
      f32x4 v = *(const f32x4*)(W + (long)(r0 + r) * 512 + c0 + tc);
#pragma unroll
      for (int j = 0; j < 4; j++) tile[(tc + j) * 72 + r] = f2bf(v[j]);
    }
    __syncthreads();
#pragma unroll
    for (int ii = 0; ii < 4; ii++) {
      int r = tr + ii * 16;     // transposed row = original col
      u16x4 o;
#pragma unroll
      for (int j = 0; j < 4; j++) o[j] = tile[r * 72 + tc + j];
      *(u16x4*)(WT + (long)(c0 + r) * 512 + r0 + tc) = o;
    }
  } else if (blk < 448) {
    int i = (blk - 192) * 256 + t;            // 65536 threads, 4 elems each
    f32x4 v = *(const f32x4*)(Wk + (long)i * 4);
    u16x4 o;
#pragma unroll
    for (int j = 0; j < 4; j++) o[j] = f2bf(v[j]);
    *(u16x4*)(wkB + (long)i * 4) = o;
  } else {
    int i = (blk - 448) * 256 + t;            // 524288 threads, 4 elems each
    int bb = i >> 7, d = (i & 127) * 4;
    int g = bb >> 7;
    f32x4 v = *(const f32x4*)(x + ((long)bb * 32 + g) * 512 + d);
    u16x4 o;
#pragma unroll
    for (int j = 0; j < 4; j++) o[j] = f2bf(v[j]);
    *(u16x4*)(xg + (long)bb * 512 + d) = o;
  }
}

// ---------------------------------------------------------------------------
// Generic TN bf16 GEMM: C[m][n] = sum_k A[m][k]*Bt[n][k] (+bias[n])
// BM x BN tile, BK=64, 4 waves (2x2), 16x16x32 MFMA, global_load_lds staging.
// DBUF: double-buffered staging -- tile k+1's loads issue BEFORE tile k's
// compute, one barrier per K-step (stage latency hides under ds_read+MFMA).
// DBUF=false only valid when K==BK (single step; G3).
// bf16 output staged through LDS for coalesced 16B stores.
// QK_SWZ: pre-swizzle the 16B-chunk position of the bf16 C-store within each
// batch's 8KB qk block (chunk bits ^= z&7) so attn's gload16->LDS staging
// yields a bank-conflict-free swizzled layout (linear DMA + permuted source).
// ---------------------------------------------------------------------------
template<int BM, int BN, int BK, bool OUT_BF16, bool CROW_REMAP, bool ADD_BIAS,
         bool QK_SWZ, bool DBUF>
__global__ __launch_bounds__(256)
void gemm_tn(const u16* __restrict__ A, int lda, long aZ,
             const u16* __restrict__ B, int ldb, long bZ,
             void* __restrict__ Cv, int ldc, long cZ,
             const float* __restrict__ bias, int biasZ, int K)
{
  constexpr int CS = BN + 8;                       // C-stage stride (16B-aligned)
  constexpr int TSZ = (BM + BN) * BK;              // u16 elems per staging buffer
  constexpr int NBUF = DBUF ? 2 : 1;
  constexpr int STG = TSZ * NBUF;
  constexpr int SMEM = (STG > BM * CS) ? STG : BM * CS;
  __shared__ u16 smem[SMEM];
  const int z = blockIdx.z;
  const u16* Ab = A + (long)z * aZ + (long)blockIdx.y * BM * lda;
  const u16* Bb = B + (long)z * bZ + (long)blockIdx.x * BN * ldb;
  const int tid = threadIdx.x;
  const int wave = tid >> 6, lane = tid & 63;
  constexpr int WM = BM / 2, WN = BN / 2;
  const int wm = wave >> 1, wn = wave & 1;
  constexpr int MF = WM / 16, NF = WN / 16;
  constexpr int ACH = (BM * BK * 2) / 1024;        // 1KB staging chunks
  constexpr int BCH = (BN * BK * 2) / 1024;
  constexpr int LPR = BK / 8;                      // lanes per row in a chunk
  constexpr int RPC = 64 / LPR;                    // rows per 1KB chunk
  f32x4 acc[MF][NF] = {};
  const int rIn  = lane / LPR;
  const int cOff = (lane % LPR) * 8;

  auto stage = [&](int kb, u16* AsD, u16* BsD) {
#pragma unroll
    for (int ch = 0; ch < ACH / 4; ch++) {
      int c = wave + ch * 4;
      int r = c * RPC + rIn;
      gload16(Ab + (long)r * lda + kb + cOff, AsD + c * 512 + lane * 8);
    }
#pragma unroll
    for (int ch = 0; ch < BCH / 4; ch++) {
      int c = wave + ch * 4;
      int r = c * RPC + rIn;
      gload16(Bb + (long)r * ldb + kb + cOff, BsD + c * 512 + lane * 8);
    }
  };

  if constexpr (DBUF) {                            // prologue: tile 0
    stage(0, smem, smem + BM * BK);
    __syncthreads();
  }
  int cur = 0;
  for (int kb = 0; kb < K; kb += BK) {
    if constexpr (DBUF) {
      if (kb + BK < K) {                           // issue next tile early
        u16* nb = smem + (cur ^ 1) * TSZ;
        stage(kb + BK, nb, nb + BM * BK);
      }
    } else {
      stage(kb, smem, smem + BM * BK);
      __syncthreads();
    }
    const u16* As = smem + cur * TSZ;
    const u16* Bs = As + BM * BK;
#pragma unroll
    for (int ks = 0; ks < BK; ks += 32) {
      s16x8 af[MF], bfv[NF];
#pragma unroll
      for (int i = 0; i < MF; i++)
        af[i] = *(const s16x8*)(As + (wm * WM + i * 16 + (lane & 15)) * BK + ks + ((lane >> 4) * 8));
#pragma unroll
      for (int j = 0; j < NF; j++)
        bfv[j] = *(const s16x8*)(Bs + (wn * WN + j * 16 + (lane & 15)) * BK + ks + ((lane >> 4) * 8));
#pragma unroll
      for (int i = 0; i < MF; i++)
#pragma unroll
        for (int j = 0; j < NF; j++)
          acc[i][j] = __builtin_amdgcn_mfma_f32_16x16x32_bf16(af[i], bfv[j], acc[i][j], 0, 0, 0);
    }
    __syncthreads();   // drains next tile's DMA + all reads of this buffer
    if constexpr (DBUF) cur ^= 1;
  }

  const long cz = (long)z * cZ;
  if constexpr (OUT_BF16) {
    // stage C in LDS (safe: last barrier already passed), then coalesced store
#pragma unroll
    for (int j = 0; j < NF; j++) {
      int colL = wn * WN + j * 16 + (lane & 15);
      float bvv = 0.f;
      if (ADD_BIAS) bvv = bias[(long)z * biasZ + blockIdx.x * BN + colL];
#pragma unroll
      for (int i = 0; i < MF; i++) {
#pragma unroll
        for (int r4 = 0; r4 < 4; r4++) {
          int rowL = wm * WM + i * 16 + ((lane >> 4) << 2) + r4;
          smem[rowL * CS + colL] = f2bf(acc[i][j][r4] + bvv);
        }
      }
    }
    __syncthreads();
    constexpr int CPR = BN / 8;                    // 8-u16 chunks per row
    constexpr int CHUNKS = BM * CPR;
    u16* Cb = (u16*)Cv + cz + (long)blockIdx.y * BM * ldc + blockIdx.x * BN;
#pragma unroll 4
    for (int c = tid; c < CHUNKS; c += 256) {
      int row = c / CPR, co = (c % CPR) * 8;
      s16x8 vv = *(const s16x8*)(smem + row * CS + co);
      int coS = QK_SWZ ? (co ^ ((z & 7) << 3)) : co;  // 16B-chunk bijection
      *(s16x8*)(Cb + (long)row * ldc + coS) = vv;
    }
  } else {
    const int colBase = blockIdx.x * BN + wn * WN;
    const int rowBase = blockIdx.y * BM + wm * WM;
#pragma unroll
    for (int j = 0; j < NF; j++) {
      int col = colBase + j * 16 + (lane & 15);
      float bvv = 0.f;
      if (ADD_BIAS) bvv = bias[(long)z * biasZ + col];
#pragma unroll
      for (int i = 0; i < MF; i++) {
#pragma unroll
        for (int r4 = 0; r4 < 4; r4++) {
          int row = rowBase + i * 16 + ((lane >> 4) << 2) + r4;
          float v = acc[i][j][r4] + bvv;
          if constexpr (CROW_REMAP) {
            // C row r -> out row (r*32 + r/128): only query row g survives
            ((float*)Cv)[((long)row * 32 + (row >> 7)) * ldc + col] = v;
          } else {
            ((float*)Cv)[cz + (long)row * ldc + col] = v;
          }
        }
      }
    }
  }
}

// ---------------------------------------------------------------------------
// attention per batch b: qk block (8KB, pre-swizzled by G3) staged to LDS via
// global_load_lds at kernel TOP (retires under x-convert + fill); bo-fill
// fused before barrier 1 (r11-proven placement); scores via MFMA on all 4
// waves, split-K; score partials + pl OVERLAY the dead qks region (one extra
// barrier) -> static LDS = 40KB = 4 blocks/CU; softmax; p_attn_sum -> d_out;
// Y = P@X (f32x2 pk-fma), written linearly over the qk buffer in place.
//
// x LDS layout: 4x16 subtiles, elem (l,d) at S*64 + (l&3)*16 + ((d&15)^((S&1)<<3)),
// S = (l>>2)*32 + (d>>4).  qk read swizzle: byte ^ (((byte>>10)&7)<<4).
// scr overlay of qks (f32): [0,256)=sclp0, [256,512)=sclp1, [512,768)=pl.
// ---------------------------------------------------------------------------
#define PSUM_OFF 67108864L

__global__ __launch_bounds__(256)
void attn_kernel(const float* __restrict__ x, u16* __restrict__ QKY,
                 const float* __restrict__ bo, float* __restrict__ out)
{
  const int b = blockIdx.x;
  const int t = threadIdx.x;
  const int wave = t >> 6, lane = t & 63;
  __shared__ u16 xs[16384];        // 32KB, subtiled
  __shared__ u16 qks[4096];        // 8KB swizzled qk; scr/pl overlay after use
  float* scr = (float*)qks;        // overlay: valid after score-read barrier

  // ---- qk -> LDS DMA, issued first (retires under x-convert + fill) ----
  const u16* qkg = QKY + (long)b * 4096;
  gload16(qkg + t * 8, qks + t * 8);
  gload16(qkg + (t + 256) * 8, qks + (t + 256) * 8);

  const f32x4* x4 = (const f32x4*)(x + (long)b * 16384);
  // x[b] -> bf16 subtiled LDS (NT loads); remap i -> (l, dq) so l&3 varies
  // across lanes (conflict-free b64 stores)
#pragma unroll
  for (int it = 0; it < 16; ++it) {
    int i = t + it * 256;
    int l = (i & 3) * 8 + (i >> 9);
    int dq = (i >> 2) & 127;
    f32x4 v = __builtin_nontemporal_load(&x4[l * 128 + dq]);
    u16x4 uv;
    uv[0] = f2bf(v[0]); uv[1] = f2bf(v[1]); uv[2] = f2bf(v[2]); uv[3] = f2bf(v[3]);
    int S = ((l >> 2) << 5) + (dq >> 2);
    int off = (S << 6) + ((l & 3) << 4) + ((((dq & 3) << 2)) ^ ((S & 1) << 3));
    *(u16x4*)(xs + off) = uv;
  }
  // bo-fill of this batch's 32 out rows (row g overwritten later by G5);
  // NT stores drain under the compute phases (r11-proven placement)
  {
    const f32x4* bo4 = (const f32x4*)bo;
    f32x4* ob = (f32x4*)(out + (long)b * 16384);
#pragma unroll
    for (int it = 0; it < 16; ++it) {
      int i = t + it * 256;
      __builtin_nontemporal_store(bo4[i & 127], &ob[i]);
    }
  }
  __syncthreads();   // bar1: qk DMA + x loads complete

  // scores^T via MFMA, all 4 waves: wave = (kw = wave>>1, lw = wave&1).
  // Each computes a 16-l tile over K-half kw (8 MFMAs).
  // qk B-frags from LDS with the G3 pre-swizzle -> conflict-free b128 reads.
  f32x4 acc = {0.f, 0.f, 0.f, 0.f};
  const int kw = wave >> 1, lw = wave & 1;
  const int brow = lane & 15;
  {
    const int l0 = lw * 16;
    const int arow = l0 + (lane & 15);
    const int fcol = (lane >> 4) * 8;
#pragma unroll
    for (int ksi = 0; ksi < 8; ksi++) {
      int d0 = (kw * 8 + ksi) * 32 + fcol;
      int S = ((arow >> 2) << 5) + (d0 >> 4);
      int aoff = (S << 6) + ((arow & 3) << 4) + ((d0 & 15) ^ ((S & 1) << 3));
      s16x8 af = *(const s16x8*)(xs + aoff);
      int qoff = brow * 1024 + d0 * 2;                 // byte off in 8KB block
      s16x8 bf = *(const s16x8*)((const char*)qks + (qoff ^ (((qoff >> 10) & 7) << 4)));
      acc = __builtin_amdgcn_mfma_f32_16x16x32_bf16(af, bf, acc, 0, 0, 0);
    }
  }
  __syncthreads();   // bar2: all waves done READING qks -> overlay writable

  if (brow < 8) {
    const int l0 = lw * 16;
#pragma unroll
    for (int r = 0; r < 4; r++)
      scr[kw * 256 + (l0 + (lane >> 4) * 4 + r) * 8 + brow] = acc[r];
  }
  __syncthreads();   // bar3: partials visible

  const int h = t >> 5, l = t & 31;
  // softmax over the 32 keys (32-lane groups, one (h,l) per thread)
  {
    float s = (scr[l * 8 + h] + scr[256 + l * 8 + h]) * 0.125f;
    float m = s;
#pragma unroll
    for (int mk = 16; mk; mk >>= 1) m = fmaxf(m, __shfl_xor(m, mk, 32));
    float ex = expf(s - m);
    float sum = ex;
#pragma unroll
    for (int mk = 16; mk; mk >>= 1) sum += __shfl_xor(sum, mk, 32);
    scr[512 + h * 32 + l] = ex / sum;      // pl
  }
  __syncthreads();   // bar4: pl visible
  if (t < 32) {
    float ps = 0.f;
#pragma unroll
    for (int hh = 0; hh < 8; hh++) ps += scr[512 + hh * 32 + t];
    out[PSUM_OFF + (long)b * 32 + t] = ps * 0.125f;
  }
  // Y[h][d] = sum_l p[h][l] x[b][l][d]; thread owns d = (t&31)*16 .. +15
  // f32x2 accumulators -> v_pk_fma_f32
  f32x2 a0p[4] = {}, a1p[4] = {};
  const int dbase = (t & 31) * 16;
  const int stag = (t >> 2) & 3;
#pragma unroll 4
  for (int i2 = 0; i2 < 32; i2++) {
    int ll = (i2 + stag) & 31;
    float pv = scr[512 + h * 32 + ll];
    f32x2 pv2 = {pv, pv};
    int S0 = ((ll >> 2) << 5) + (t & 31);
    int base = (S0 << 6) + ((ll & 3) << 4);
    int sw = (S0 & 1) << 3;
    u32x4 xa = *(const u32x4*)(xs + base + sw);        // d..d+7
    u32x4 xc = *(const u32x4*)(xs + base + (8 ^ sw));  // d+8..d+15
#pragma unroll
    for (int e2 = 0; e2 < 4; e2++) {
      f32x2 xp0, xp1;
      xp0[0] = u2f(xa[e2] << 16); xp0[1] = u2f(xa[e2] & 0xFFFF0000u);
      xp1[0] = u2f(xc[e2] << 16); xp1[1] = u2f(xc[e2] & 0xFFFF0000u);
      a0p[e2] += xp0 * pv2;
      a1p[e2] += xp1 * pv2;
    }
  }
  u16* yrow = QKY + (long)b * 4096 + h * 512 + dbase;  // linear Y (G4 reads it)
  s16x8 o0, o1;
#pragma unroll
  for (int e2 = 0; e2 < 4; e2++) {
    o0[e2 * 2]     = (short)f2bf(a0p[e2][0]);
    o0[e2 * 2 + 1] = (short)f2bf(a0p[e2][1]);
    o1[e2 * 2]     = (short)f2bf(a1p[e2][0]);
    o1[e2 * 2 + 1] = (short)f2bf(a1p[e2][1]);
  }
  *(s16x8*)(yrow) = o0;
  *(s16x8*)(yrow + 8) = o1;
}

// ---------------------------------------------------------------------------
extern "C" void kernel_launch(void* const* d_in, const int* in_sizes, int n_in,
                              void* d_out, int out_size, void* d_ws, size_t ws_size,
                              hipStream_t stream)
{
  const float* x  = (const float*)d_in[0];
  const float* Wq = (const float*)d_in[1];
  const float* bq = (const float*)d_in[2];
  const float* Wk = (const float*)d_in[3];
  // d_in[4] = bk: drops out (softmax shift-invariance over keys)
  const float* Wv = (const float*)d_in[5];
  const float* bv = (const float*)d_in[6];
  const float* Wo = (const float*)d_in[7];
  const float* bo = (const float*)d_in[8];
  float* out = (float*)d_out;

  char* w = (char*)d_ws;
  u16* wqT = (u16*)(w);              // 512x512 bf16
  u16* wkB = (u16*)(w + 524288);
  u16* wvT = (u16*)(w + 1048576);
  u16* woT = (u16*)(w + 1572864);
  u16* xg  = (u16*)(w + 2097152);    // 4096x512 bf16
  u16* qbf = (u16*)(w + 6291456);    // 4096x512 bf16
  u16* qky = (u16*)(w + 10485760);   // 4096x4096 bf16 (QK swizzled, then Y linear)
  u16* ctx = (u16*)(w + 44040192);   // 4096x512 bf16

  prep_kernel<<<2496, 256, 0, stream>>>(x, Wq, Wv, Wo, Wk, wqT, wvT, woT, wkB, xg);
  // Q = Xg @ Wq + bq          (M=4096,N=512,K=512) -> bf16, 64x64, dbuf
  gemm_tn<64, 64, 64, true, false, true, false, true><<<dim3(8, 64, 1), 256, 0, stream>>>(
      xg, 512, 0, wqT, 512, 0, qbf, 512, 0, bq, 0, 512);
  // QK[h] = Q_h @ Wk_h^T      (M=4096,N=512,K=64, z=8) -> bf16, PRE-SWIZZLED
  gemm_tn<128, 128, 64, true, false, false, true, false><<<dim3(4, 32, 8), 256, 0, stream>>>(
      qbf, 512, 64, wkB, 512, 64, qky, 4096, 512, nullptr, 0, 64);
  // attention + bo-fill + p_attn_sum; Y overwrites qky
  attn_kernel<<<4096, 256, 0, stream>>>(x, qky, bo, out);
  // CTX[h] = Y_h @ Wv_h + bv  (M=4096,N=64,K=512, z=8) -> bf16, dbuf
  gemm_tn<64, 64, 64, true, false, true, false, true><<<dim3(1, 64, 8), 256, 0, stream>>>(
      qky, 4096, 512, wvT, 512, 32768, ctx, 512, 64, bv, 64, 512);
  // out[b, g, :] = CTX @ Wo + bo  (scatter rows; fill already done), dbuf
  gemm_tn<64, 64, 64, false, true, true, false, true><<<dim3(8, 64, 1), 256, 0, stream>>>(
      ctx, 512, 0, woT, 512, 0, out, 512, 0, bo, 0, 512);
}

// Round 14
// 145.880 us; speedup vs baseline: 1.0285x; 1.0285x over previous
//
#include <hip/hip_runtime.h>
#include <hip/hip_bf16.h>
#include <math.h>

typedef unsigned short u16;
typedef __attribute__((ext_vector_type(2))) float f32x2;
typedef __attribute__((ext_vector_type(4))) float f32x4;
typedef __attribute__((ext_vector_type(4))) unsigned short u16x4;
typedef __attribute__((ext_vector_type(8))) short s16x8;
typedef __attribute__((ext_vector_type(4))) unsigned int u32x4;

__device__ __forceinline__ u16 f2bf(float f) {
  union { float f; unsigned int u; } v; v.f = f;
  unsigned int r = v.u + 0x7FFFu + ((v.u >> 16) & 1u);
  return (u16)(r >> 16);
}
__device__ __forceinline__ float bf2f(u16 u) {
  union { unsigned int u; float f; } v; v.u = ((unsigned int)u) << 16;
  return v.f;
}
__device__ __forceinline__ float u2f(unsigned int u) {
  union { unsigned int u; float f; } v; v.u = u;
  return v.f;
}
__device__ __forceinline__ void gload16(const void* g, void* l) {
  __builtin_amdgcn_global_load_lds(
      (const __attribute__((address_space(1))) unsigned int*)g,
      (__attribute__((address_space(3))) unsigned int*)l, 16, 0, 0);
}

// ---------------------------------------------------------------------------
// prep: blocks [0,192): LDS-tiled transpose of Wq/Wv/Wo -> bf16 (coalesced
// both sides); [192,448): Wk straight convert; [448,2496): xg row gather.
// ---------------------------------------------------------------------------
__global__ __launch_bounds__(256)
void prep_kernel(const float* __restrict__ x,
                 const float* __restrict__ Wq, const float* __restrict__ Wv,
                 const float* __restrict__ Wo, const float* __restrict__ Wk,
                 u16* __restrict__ wqT, u16* __restrict__ wvT,
                 u16* __restrict__ woT, u16* __restrict__ wkB,
                 u16* __restrict__ xg)
{
  const int blk = blockIdx.x;
  const int t = threadIdx.x;
  if (blk < 192) {
    __shared__ u16 tile[64 * 72];
    int m = blk >> 6, tno = blk & 63;
    const float* W = (m == 0) ? Wq : (m == 1) ? Wv : Wo;
    u16* WT = (m == 0) ? wqT : (m == 1) ? wvT : woT;
    int r0 = (tno >> 3) * 64, c0 = (tno & 7) * 64;
    int tr = t >> 4;            // 0..15
    int tc = (t & 15) * 4;      // 0..60
#pragma unroll
    for (int ii = 0; ii < 4; ii++) {
      int r = tr + ii * 16;
      f32x4 v = *(const f32x4*)(W + (long)(r0 + r) * 512 + c0 + tc);
#pragma unroll
      for (int j = 0; j < 4; j++) tile[(tc + j) * 72 + r] = f2bf(v[j]);
    }
    __syncthreads();
#pragma unroll
    for (int ii = 0; ii < 4; ii++) {
      int r = tr + ii * 16;     // transposed row = original col
      u16x4 o;
#pragma unroll
      for (int j = 0; j < 4; j++) o[j] = tile[r * 72 + tc + j];
      *(u16x4*)(WT + (long)(c0 + r) * 512 + r0 + tc) = o;
    }
  } else if (blk < 448) {
    int i = (blk - 192) * 256 + t;            // 65536 threads, 4 elems each
    f32x4 v = *(const f32x4*)(Wk + (long)i * 4);
    u16x4 o;
#pragma unroll
    for (int j = 0; j < 4; j++) o[j] = f2bf(v[j]);
    *(u16x4*)(wkB + (long)i * 4) = o;
  } else {
    int i = (blk - 448) * 256 + t;            // 524288 threads, 4 elems each
    int bb = i >> 7, d = (i & 127) * 4;
    int g = bb >> 7;
    f32x4 v = *(const f32x4*)(x + ((long)bb * 32 + g) * 512 + d);
    u16x4 o;
#pragma unroll
    for (int j = 0; j < 4; j++) o[j] = f2bf(v[j]);
    *(u16x4*)(xg + (long)bb * 512 + d) = o;
  }
}

// ---------------------------------------------------------------------------
// Generic TN bf16 GEMM: C[m][n] = sum_k A[m][k]*Bt[n][k] (+bias[n])
// BM x BN tile, BK=64, 4 waves (2x2), 16x16x32 MFMA, global_load_lds staging.
// DBUF: double-buffered staging -- tile k+1's loads issue BEFORE tile k's
// compute, one barrier per K-step (stage latency hides under ds_read+MFMA).
// DBUF=false only valid when K==BK (single step; G3).
// bf16 output staged through LDS for coalesced 16B stores.
// QK_SWZ: pre-swizzle the 16B-chunk position of the bf16 C-store within each
// batch's 8KB qk block (chunk bits ^= z&7) so attn's gload16->LDS staging
// yields a bank-conflict-free swizzled layout (linear DMA + permuted source).
// ---------------------------------------------------------------------------
template<int BM, int BN, int BK, bool OUT_BF16, bool CROW_REMAP, bool ADD_BIAS,
         bool QK_SWZ, bool DBUF>
__global__ __launch_bounds__(256)
void gemm_tn(const u16* __restrict__ A, int lda, long aZ,
             const u16* __restrict__ B, int ldb, long bZ,
             void* __restrict__ Cv, int ldc, long cZ,
             const float* __restrict__ bias, int biasZ, int K)
{
  constexpr int CS = BN + 8;                       // C-stage stride (16B-aligned)
  constexpr int TSZ = (BM + BN) * BK;              // u16 elems per staging buffer
  constexpr int NBUF = DBUF ? 2 : 1;
  constexpr int STG = TSZ * NBUF;
  constexpr int SMEM = (STG > BM * CS) ? STG : BM * CS;
  __shared__ u16 smem[SMEM];
  const int z = blockIdx.z;
  const u16* Ab = A + (long)z * aZ + (long)blockIdx.y * BM * lda;
  const u16* Bb = B + (long)z * bZ + (long)blockIdx.x * BN * ldb;
  const int tid = threadIdx.x;
  const int wave = tid >> 6, lane = tid & 63;
  constexpr int WM = BM / 2, WN = BN / 2;
  const int wm = wave >> 1, wn = wave & 1;
  constexpr int MF = WM / 16, NF = WN / 16;
  constexpr int ACH = (BM * BK * 2) / 1024;        // 1KB staging chunks
  constexpr int BCH = (BN * BK * 2) / 1024;
  constexpr int LPR = BK / 8;                      // lanes per row in a chunk
  constexpr int RPC = 64 / LPR;                    // rows per 1KB chunk
  f32x4 acc[MF][NF] = {};
  const int rIn  = lane / LPR;
  const int cOff = (lane % LPR) * 8;

  auto stage = [&](int kb, u16* AsD, u16* BsD) {
#pragma unroll
    for (int ch = 0; ch < ACH / 4; ch++) {
      int c = wave + ch * 4;
      int r = c * RPC + rIn;
      gload16(Ab + (long)r * lda + kb + cOff, AsD + c * 512 + lane * 8);
    }
#pragma unroll
    for (int ch = 0; ch < BCH / 4; ch++) {
      int c = wave + ch * 4;
      int r = c * RPC + rIn;
      gload16(Bb + (long)r * ldb + kb + cOff, BsD + c * 512 + lane * 8);
    }
  };

  if constexpr (DBUF) {                            // prologue: tile 0
    stage(0, smem, smem + BM * BK);
    __syncthreads();
  }
  int cur = 0;
  for (int kb = 0; kb < K; kb += BK) {
    if constexpr (DBUF) {
      if (kb + BK < K) {                           // issue next tile early
        u16* nb = smem + (cur ^ 1) * TSZ;
        stage(kb + BK, nb, nb + BM * BK);
      }
    } else {
      stage(kb, smem, smem + BM * BK);
      __syncthreads();
    }
    const u16* As = smem + cur * TSZ;
    const u16* Bs = As + BM * BK;
#pragma unroll
    for (int ks = 0; ks < BK; ks += 32) {
      s16x8 af[MF], bfv[NF];
#pragma unroll
      for (int i = 0; i < MF; i++)
        af[i] = *(const s16x8*)(As + (wm * WM + i * 16 + (lane & 15)) * BK + ks + ((lane >> 4) * 8));
#pragma unroll
      for (int j = 0; j < NF; j++)
        bfv[j] = *(const s16x8*)(Bs + (wn * WN + j * 16 + (lane & 15)) * BK + ks + ((lane >> 4) * 8));
#pragma unroll
      for (int i = 0; i < MF; i++)
#pragma unroll
        for (int j = 0; j < NF; j++)
          acc[i][j] = __builtin_amdgcn_mfma_f32_16x16x32_bf16(af[i], bfv[j], acc[i][j], 0, 0, 0);
    }
    __syncthreads();   // drains next tile's DMA + all reads of this buffer
    if constexpr (DBUF) cur ^= 1;
  }

  const long cz = (long)z * cZ;
  if constexpr (OUT_BF16) {
    // stage C in LDS (safe: last barrier already passed), then coalesced store
#pragma unroll
    for (int j = 0; j < NF; j++) {
      int colL = wn * WN + j * 16 + (lane & 15);
      float bvv = 0.f;
      if (ADD_BIAS) bvv = bias[(long)z * biasZ + blockIdx.x * BN + colL];
#pragma unroll
      for (int i = 0; i < MF; i++) {
#pragma unroll
        for (int r4 = 0; r4 < 4; r4++) {
          int rowL = wm * WM + i * 16 + ((lane >> 4) << 2) + r4;
          smem[rowL * CS + colL] = f2bf(acc[i][j][r4] + bvv);
        }
      }
    }
    __syncthreads();
    constexpr int CPR = BN / 8;                    // 8-u16 chunks per row
    constexpr int CHUNKS = BM * CPR;
    u16* Cb = (u16*)Cv + cz + (long)blockIdx.y * BM * ldc + blockIdx.x * BN;
#pragma unroll 4
    for (int c = tid; c < CHUNKS; c += 256) {
      int row = c / CPR, co = (c % CPR) * 8;
      s16x8 vv = *(const s16x8*)(smem + row * CS + co);
      int coS = QK_SWZ ? (co ^ ((z & 7) << 3)) : co;  // 16B-chunk bijection
      *(s16x8*)(Cb + (long)row * ldc + coS) = vv;
    }
  } else {
    const int colBase = blockIdx.x * BN + wn * WN;
    const int rowBase = blockIdx.y * BM + wm * WM;
#pragma unroll
    for (int j = 0; j < NF; j++) {
      int col = colBase + j * 16 + (lane & 15);
      float bvv = 0.f;
      if (ADD_BIAS) bvv = bias[(long)z * biasZ + col];
#pragma unroll
      for (int i = 0; i < MF; i++) {
#pragma unroll
        for (int r4 = 0; r4 < 4; r4++) {
          int row = rowBase + i * 16 + ((lane >> 4) << 2) + r4;
          float v = acc[i][j][r4] + bvv;
          if constexpr (CROW_REMAP) {
            // C row r -> out row (r*32 + r/128): only query row g survives
            ((float*)Cv)[((long)row * 32 + (row >> 7)) * ldc + col] = v;
          } else {
            ((float*)Cv)[cz + (long)row * ldc + col] = v;
          }
        }
      }
    }
  }
}

// ---------------------------------------------------------------------------
// attention per batch b: qk block (8KB, pre-swizzled by G3) staged to LDS via
// global_load_lds at kernel TOP (retires under the x-convert phase); scores
// via MFMA on all 4 waves, split-K; softmax; bo-fill fused BEFORE barrier 1
// (r11-proven placement: NT stores drain under all compute phases);
// p_attn_sum -> d_out; Y = P@X (f32x2 pk-fma), written linearly over the qk
// buffer in place.
//
// x LDS layout: 4x16 subtiles, elem (l,d) at S*64 + (l&3)*16 + ((d&15)^((S&1)<<3)),
// S = (l>>2)*32 + (d>>4).  qk read swizzle: byte ^ (((byte>>10)&7)<<4).
// ---------------------------------------------------------------------------
#define PSUM_OFF 67108864L

__global__ __launch_bounds__(256)
void attn_kernel(const float* __restrict__ x, u16* __restrict__ QKY,
                 const float* __restrict__ bo, float* __restrict__ out)
{
  const int b = blockIdx.x;
  const int t = threadIdx.x;
  const int wave = t >> 6, lane = t & 63;
  __shared__ u16 xs[16384];        // 32KB, subtiled
  __shared__ u16 qks[4096];        // 8KB swizzled qk; pl overlays after scores
  __shared__ float sclp[2][256];
  float* pl = (float*)qks;         // overlay: qks dead after score barrier

  // ---- qk -> LDS DMA, issued first (retires under x-convert + fill) ----
  const u16* qkg = QKY + (long)b * 4096;
  gload16(qkg + t * 8, qks + t * 8);
  gload16(qkg + (t + 256) * 8, qks + (t + 256) * 8);

  const f32x4* x4 = (const f32x4*)(x + (long)b * 16384);
  // x[b] -> bf16 subtiled LDS (NT loads); remap i -> (l, dq) so l&3 varies
  // across lanes (conflict-free b64 stores)
#pragma unroll
  for (int it = 0; it < 16; ++it) {
    int i = t + it * 256;
    int l = (i & 3) * 8 + (i >> 9);
    int dq = (i >> 2) & 127;
    f32x4 v = __builtin_nontemporal_load(&x4[l * 128 + dq]);
    u16x4 uv;
    uv[0] = f2bf(v[0]); uv[1] = f2bf(v[1]); uv[2] = f2bf(v[2]); uv[3] = f2bf(v[3]);
    int S = ((l >> 2) << 5) + (dq >> 2);
    int off = (S << 6) + ((l & 3) << 4) + ((((dq & 3) << 2)) ^ ((S & 1) << 3));
    *(u16x4*)(xs + off) = uv;
  }
  // bo-fill of this batch's 32 out rows (row g overwritten later by G5);
  // NT stores drain under the compute phases (r11-proven placement)
  {
    const f32x4* bo4 = (const f32x4*)bo;
    f32x4* ob = (f32x4*)(out + (long)b * 16384);
#pragma unroll
    for (int it = 0; it < 16; ++it) {
      int i = t + it * 256;
      __builtin_nontemporal_store(bo4[i & 127], &ob[i]);
    }
  }
  __syncthreads();   // drains vmcnt: qk DMA + x loads complete

  // scores^T via MFMA, all 4 waves: wave = (kw = wave>>1, lw = wave&1).
  // Each computes a 16-l tile over K-half kw (8 MFMAs); partials to sclp[kw].
  // qk B-frags from LDS with the G3 pre-swizzle -> conflict-free b128 reads.
  {
    const int kw = wave >> 1, lw = wave & 1;
    const int l0 = lw * 16;
    const int arow = l0 + (lane & 15);
    const int brow = lane & 15;
    const int fcol = (lane >> 4) * 8;
    f32x4 acc = {0.f, 0.f, 0.f, 0.f};
#pragma unroll
    for (int ksi = 0; ksi < 8; ksi++) {
      int d0 = (kw * 8 + ksi) * 32 + fcol;
      int S = ((arow >> 2) << 5) + (d0 >> 4);
      int aoff = (S << 6) + ((arow & 3) << 4) + ((d0 & 15) ^ ((S & 1) << 3));
      s16x8 af = *(const s16x8*)(xs + aoff);
      int qoff = brow * 1024 + d0 * 2;                 // byte off in 8KB block
      s16x8 bf = *(const s16x8*)((const char*)qks + (qoff ^ (((qoff >> 10) & 7) << 4)));
      acc = __builtin_amdgcn_mfma_f32_16x16x32_bf16(af, bf, acc, 0, 0, 0);
    }
    if (brow < 8) {
#pragma unroll
      for (int r = 0; r < 4; r++)
        sclp[kw][(l0 + (lane >> 4) * 4 + r) * 8 + brow] = acc[r];
    }
  }
  __syncthreads();   // qks dead from here; pl overlay becomes valid

  const int h = t >> 5, l = t & 31;
  // softmax over the 32 keys (32-lane groups, one (h,l) per thread)
  {
    float s = (sclp[0][l * 8 + h] + sclp[1][l * 8 + h]) * 0.125f;
    float m = s;
#pragma unroll
    for (int mk = 16; mk; mk >>= 1) m = fmaxf(m, __shfl_xor(m, mk, 32));
    float ex = expf(s - m);
    float sum = ex;
#pragma unroll
    for (int mk = 16; mk; mk >>= 1) sum += __shfl_xor(sum, mk, 32);
    pl[h * 32 + l] = ex / sum;
  }
  __syncthreads();
  if (t < 32) {
    float ps = 0.f;
#pragma unroll
    for (int hh = 0; hh < 8; hh++) ps += pl[hh * 32 + t];
    out[PSUM_OFF + (long)b * 32 + t] = ps * 0.125f;
  }
  // Y[h][d] = sum_l p[h][l] x[b][l][d]; thread owns d = (t&31)*16 .. +15
  // f32x2 accumulators -> v_pk_fma_f32
  f32x2 a0p[4] = {}, a1p[4] = {};
  const int dbase = (t & 31) * 16;
  const int stag = (t >> 2) & 3;
#pragma unroll 4
  for (int i2 = 0; i2 < 32; i2++) {
    int ll = (i2 + stag) & 31;
    float pv = pl[h * 32 + ll];
    f32x2 pv2 = {pv, pv};
    int S0 = ((ll >> 2) << 5) + (t & 31);
    int base = (S0 << 6) + ((ll & 3) << 4);
    int sw = (S0 & 1) << 3;
    u32x4 xa = *(const u32x4*)(xs + base + sw);        // d..d+7
    u32x4 xc = *(const u32x4*)(xs + base + (8 ^ sw));  // d+8..d+15
#pragma unroll
    for (int e2 = 0; e2 < 4; e2++) {
      f32x2 xp0, xp1;
      xp0[0] = u2f(xa[e2] << 16); xp0[1] = u2f(xa[e2] & 0xFFFF0000u);
      xp1[0] = u2f(xc[e2] << 16); xp1[1] = u2f(xc[e2] & 0xFFFF0000u);
      a0p[e2] += xp0 * pv2;
      a1p[e2] += xp1 * pv2;
    }
  }
  u16* yrow = QKY + (long)b * 4096 + h * 512 + dbase;  // linear Y (G4 reads it)
  s16x8 o0, o1;
#pragma unroll
  for (int e2 = 0; e2 < 4; e2++) {
    o0[e2 * 2]     = (short)f2bf(a0p[e2][0]);
    o0[e2 * 2 + 1] = (short)f2bf(a0p[e2][1]);
    o1[e2 * 2]     = (short)f2bf(a1p[e2][0]);
    o1[e2 * 2 + 1] = (short)f2bf(a1p[e2][1]);
  }
  *(s16x8*)(yrow) = o0;
  *(s16x8*)(yrow + 8) = o1;
}

// ---------------------------------------------------------------------------
extern "C" void kernel_launch(void* const* d_in, const int* in_sizes, int n_in,
                              void* d_out, int out_size, void* d_ws, size_t ws_size,
                              hipStream_t stream)
{
  const float* x  = (const float*)d_in[0];
  const float* Wq = (const float*)d_in[1];
  const float* bq = (const float*)d_in[2];
  const float* Wk = (const float*)d_in[3];
  // d_in[4] = bk: drops out (softmax shift-invariance over keys)
  const float* Wv = (const float*)d_in[5];
  const float* bv = (const float*)d_in[6];
  const float* Wo = (const float*)d_in[7];
  const float* bo = (const float*)d_in[8];
  float* out = (float*)d_out;

  char* w = (char*)d_ws;
  u16* wqT = (u16*)(w);              // 512x512 bf16
  u16* wkB = (u16*)(w + 524288);
  u16* wvT = (u16*)(w + 1048576);
  u16* woT = (u16*)(w + 1572864);
  u16* xg  = (u16*)(w + 2097152);    // 4096x512 bf16
  u16* qbf = (u16*)(w + 6291456);    // 4096x512 bf16
  u16* qky = (u16*)(w + 10485760);   // 4096x4096 bf16 (QK swizzled, then Y linear)
  u16* ctx = (u16*)(w + 44040192);   // 4096x512 bf16

  prep_kernel<<<2496, 256, 0, stream>>>(x, Wq, Wv, Wo, Wk, wqT, wvT, woT, wkB, xg);
  // Q = Xg @ Wq + bq          (M=4096,N=512,K=512) -> bf16, 64x64, dbuf
  gemm_tn<64, 64, 64, true, false, true, false, true><<<dim3(8, 64, 1), 256, 0, stream>>>(
      xg, 512, 0, wqT, 512, 0, qbf, 512, 0, bq, 0, 512);
  // QK[h] = Q_h @ Wk_h^T      (M=4096,N=512,K=64, z=8) -> bf16, PRE-SWIZZLED
  gemm_tn<128, 128, 64, true, false, false, true, false><<<dim3(4, 32, 8), 256, 0, stream>>>(
      qbf, 512, 64, wkB, 512, 64, qky, 4096, 512, nullptr, 0, 64);
  // attention + bo-fill + p_attn_sum; Y overwrites qky
  attn_kernel<<<4096, 256, 0, stream>>>(x, qky, bo, out);
  // CTX[h] = Y_h @ Wv_h + bv  (M=4096,N=64,K=512, z=8) -> bf16, dbuf
  gemm_tn<64, 64, 64, true, false, true, false, true><<<dim3(1, 64, 8), 256, 0, stream>>>(
      qky, 4096, 512, wvT, 512, 32768, ctx, 512, 64, bv, 64, 512);
  // out[b, g, :] = CTX @ Wo + bo  (scatter rows; fill already done), dbuf
  gemm_tn<64, 64, 64, false, true, true, false, true><<<dim3(8, 64, 1), 256, 0, stream>>>(
      ctx, 512, 0, woT, 512, 0, out, 512, 0, bo, 0, 512);
}